// Round 4
// baseline (7042.050 us; speedup 1.0000x reference)
//
#include <hip/hip_runtime.h>

// ---------------------------------------------------------------------------
// FlowMatchingShield: 50-step Euler sampler over a 5-layer MLP.
//   h = concat([state(254), x(2), temb(64)])  -> 320
//   h @ W0 split:  base = state@W0[0:254]+b0  (once)
//                  tvec[s] = temb(s)@W0[256:320] (once, 50 vectors)
//                  x-part = x@W0[254:256]  (elementwise per step)
//
// Round 4: round 3's persistent kernel (one kernel, 50 steps, 2-level atomic
// grid barrier) with the TAIL bug fixed: layer 3's output needs SiLU before
// the W4 head dot (round 3 omitted it -> absmax 0.297). No other changes.
// Grid 16x16=256 blocks (1/CU co-resident), 512 threads. Per step:
// h0 | L1 | L2 | L3+tail, 4 grid barriers. h3 never touches global.
// ---------------------------------------------------------------------------

typedef __bf16 bf16x8 __attribute__((ext_vector_type(8)));
typedef float  f32x4  __attribute__((ext_vector_type(4)));
typedef float  f32x2  __attribute__((ext_vector_type(2)));
typedef unsigned short u16;
typedef u16 u16x8 __attribute__((ext_vector_type(8)));
typedef u16 u16x4 __attribute__((ext_vector_type(4)));
typedef u16 u16x2 __attribute__((ext_vector_type(2)));

#define H 1024
#define BATCH 1024
#define SDIM 254
#define NSTEP 50
#define DT 0.02f

__device__ __forceinline__ u16 f2bf(float f) {
  unsigned int u = __float_as_uint(f);
  return (u16)((u + 0x7FFFu + ((u >> 16) & 1u)) >> 16);
}

__device__ __forceinline__ float silu(float v) {
  return v / (1.0f + __expf(-v));
}

// --- one-time: W[k][n] fp32 -> WT[n][k] bf16, for W1..W3 (blockIdx.z picks) --
__global__ void transpose_w(const float* __restrict__ A, const float* __restrict__ B,
                            const float* __restrict__ C, u16* __restrict__ TA,
                            u16* __restrict__ TB, u16* __restrict__ TC) {
  const float* W = (blockIdx.z == 0) ? A : (blockIdx.z == 1) ? B : C;
  u16* T = (blockIdx.z == 0) ? TA : (blockIdx.z == 1) ? TB : TC;
  __shared__ float tile[32][33];
  const int n0 = blockIdx.x * 32, k0 = blockIdx.y * 32;
  const int tx = threadIdx.x & 31, ty = threadIdx.x >> 5;  // 32 x 8
#pragma unroll
  for (int i = 0; i < 4; ++i)
    tile[ty + 8 * i][tx] = W[(k0 + ty + 8 * i) * H + n0 + tx];
  __syncthreads();
#pragma unroll
  for (int i = 0; i < 4; ++i)
    T[(size_t)(n0 + ty + 8 * i) * H + k0 + tx] = f2bf(tile[tx][ty + 8 * i]);
}

// --- one-time: base[b][n] = b0[n] + sum_k state[b][k]*W0[k][n] (k<254) -------
__global__ __launch_bounds__(256) void base_gemm(const float* __restrict__ state,
                                                 const float* __restrict__ W0,
                                                 const float* __restrict__ b0,
                                                 float* __restrict__ base) {
  __shared__ float Sst[64][68];
  __shared__ float Wl[64][68];
  const int bc = blockIdx.x, br = blockIdx.y, tid = threadIdx.x;
  const int myrow = (tid >> 4) * 4;
  const int mycol = (tid & 15) * 4;
  const int lr = tid >> 2;
  const int lc = (tid & 3) * 16;
  f32x4 acc[4] = {};

  for (int kc = 0; kc < 4; ++kc) {
    const int k0 = kc * 64;
#pragma unroll
    for (int j = 0; j < 8; ++j) {
      const int k = k0 + lc + 2 * j;
      float vx = 0.f, vy = 0.f;
      if (k + 1 < SDIM) {
        float2 v = *(const float2*)&state[(size_t)(br * 64 + lr) * SDIM + k];
        vx = v.x; vy = v.y;
      } else if (k < SDIM) {
        vx = state[(size_t)(br * 64 + lr) * SDIM + k];
      }
      Sst[lr][lc + 2 * j] = vx;
      Sst[lr][lc + 2 * j + 1] = vy;
    }
#pragma unroll
    for (int j = 0; j < 4; ++j) {
      f32x4 wv = {};
      if (k0 + lr < SDIM)
        wv = *(const f32x4*)&W0[(size_t)(k0 + lr) * H + bc * 64 + lc + 4 * j];
      *(f32x4*)&Wl[lr][lc + 4 * j] = wv;
    }
    __syncthreads();
#pragma unroll 4
    for (int kk = 0; kk < 64; kk += 4) {
      f32x4 sv[4], wv[4];
#pragma unroll
      for (int r = 0; r < 4; ++r) sv[r] = *(const f32x4*)&Sst[myrow + r][kk];
#pragma unroll
      for (int j = 0; j < 4; ++j) wv[j] = *(const f32x4*)&Wl[kk + j][mycol];
#pragma unroll
      for (int r = 0; r < 4; ++r)
#pragma unroll
        for (int j = 0; j < 4; ++j)
          acc[r] += sv[r][j] * wv[j];
    }
    __syncthreads();
  }

  const f32x4 bv = *(const f32x4*)&b0[bc * 64 + mycol];
#pragma unroll
  for (int r = 0; r < 4; ++r) {
    f32x4 o = acc[r] + bv;
    *(f32x4*)&base[(size_t)(br * 64 + myrow + r) * H + bc * 64 + mycol] = o;
  }
}

// --- one-time: tvec[s][h] = sum_j sin(t fj) W0[256+j][h] + cos(t fj) W0[288+j][h]
__global__ void tvec_kernel(const float* __restrict__ W0, float* __restrict__ tvec) {
  const int s = blockIdx.x;
  const int h = blockIdx.y * 256 + threadIdx.x;
  const float t = (float)s * DT;
  float acc = 0.0f;
#pragma unroll
  for (int j = 0; j < 32; ++j) {
    float fr = __expf((float)j * (-9.210340371976184f / 31.0f));
    float ang = t * fr;
    acc += __sinf(ang) * W0[(256 + j) * H + h] + __cosf(ang) * W0[(288 + j) * H + h];
  }
  tvec[s * H + h] = acc;
}

// --- one-time: zero the grid-barrier counters (ws is poisoned each call) ----
__global__ void bar_init(unsigned int* __restrict__ bar) {
  bar[threadIdx.x] = 0u;
  bar[threadIdx.x + 256] = 0u;
  bar[threadIdx.x + 512] = 0u;
  bar[threadIdx.x + 768] = 0u;
}

// --- 2-level grid barrier: 16 leaves (blockIdx.x) x 16 blocks, then root ----
__device__ __forceinline__ void gsync(unsigned int* bar, unsigned int phase) {
  __syncthreads();
  if (threadIdx.x == 0) {
    __threadfence();  // release: make this block's writes device-visible
    unsigned int* leaf = bar + (blockIdx.x << 5);  // 128B apart
    unsigned int v = __hip_atomic_fetch_add(leaf, 1u, __ATOMIC_ACQ_REL,
                                            __HIP_MEMORY_SCOPE_AGENT);
    if (v == phase * 16u - 1u) {  // last of this 16-block leaf
      unsigned int r = __hip_atomic_fetch_add(bar + 512, 1u, __ATOMIC_ACQ_REL,
                                              __HIP_MEMORY_SCOPE_AGENT);
      if (r == phase * 16u - 1u)  // last leaf
        __hip_atomic_store(bar + 544, phase, __ATOMIC_RELEASE,
                           __HIP_MEMORY_SCOPE_AGENT);
    }
    while (__hip_atomic_load(bar + 544, __ATOMIC_ACQUIRE,
                             __HIP_MEMORY_SCOPE_AGENT) < phase)
      __builtin_amdgcn_s_sleep(2);
    __threadfence();  // acquire: invalidate stale cached lines
  }
  __syncthreads();
}

// --- one GEMM layer phase: out = silu(A @ BT^T + bias)  [TAIL=0]
//     or h3 = silu(A @ BT^T + b3); vpart[bn][row] = h3 . W4  [TAIL=1, no h3 write]
template <int TAIL>
__device__ __forceinline__ void layer_phase(const u16* __restrict__ A,
                                            const u16* __restrict__ BT,
                                            const float* __restrict__ bias,
                                            u16* __restrict__ outp,
                                            const float* __restrict__ W4,
                                            float* __restrict__ vpart,
                                            int bn, int bm, int w, int lane, int tid,
                                            float (*red)[16][68]) {
  const int lr = lane & 15, quad = lane >> 4;
  // wave w owns k in [w*128, (w+1)*128): 4 k-iters of 32, all loads up-front
  const u16* Ap = A + (size_t)(bm * 64 + lr) * H + w * 128 + quad * 8;
  const u16* Bp = BT + (size_t)(bn * 64 + lr) * H + w * 128 + quad * 8;

  bf16x8 fa[4][4], fb[4][4];
#pragma unroll
  for (int it = 0; it < 4; ++it)
#pragma unroll
    for (int q = 0; q < 4; ++q) {
      fa[it][q] = *(const bf16x8*)(Ap + q * 16 * H + it * 32);
      fb[it][q] = *(const bf16x8*)(Bp + q * 16 * H + it * 32);
    }

  f32x4 acc[4][4] = {};
#pragma unroll
  for (int it = 0; it < 4; ++it)
#pragma unroll
    for (int mt = 0; mt < 4; ++mt)
#pragma unroll
      for (int nt = 0; nt < 4; ++nt)
        acc[mt][nt] = __builtin_amdgcn_mfma_f32_16x16x32_bf16(fa[it][mt], fb[it][nt],
                                                              acc[mt][nt], 0, 0, 0);

  // cross-wave K-reduction, 4 phases of 16 rows
  const int m = tid >> 5, n0 = (tid & 31) * 2;
  const f32x2 bv = *(const f32x2*)&bias[bn * 64 + n0];
  f32x4 w4v = {};
  if (TAIL) w4v = *(const f32x4*)&W4[2 * (bn * 64 + n0)];
#pragma unroll
  for (int p = 0; p < 4; ++p) {
    if (p) __syncthreads();  // WAR vs previous phase's reads
#pragma unroll
    for (int nt = 0; nt < 4; ++nt)
#pragma unroll
      for (int r = 0; r < 4; ++r)
        red[w][quad * 4 + r][nt * 16 + lr] = acc[p][nt][r];
    __syncthreads();
    f32x2 sv = {};
#pragma unroll
    for (int ww = 0; ww < 8; ++ww) sv += *(const f32x2*)&red[ww][m][n0];
    const int gm = bm * 64 + p * 16 + m;
    if (!TAIL) {
      u16x2 o = {f2bf(silu(sv[0] + bv[0])), f2bf(silu(sv[1] + bv[1]))};
      *(u16x2*)&outp[(size_t)gm * H + bn * 64 + n0] = o;
    } else {
      // FIX (round 4): layer 3 output needs SiLU before the W4 head dot.
      const float t0 = silu(sv[0] + bv[0]), t1 = silu(sv[1] + bv[1]);
      float pv0 = t0 * w4v[0] + t1 * w4v[2];
      float pv1 = t0 * w4v[1] + t1 * w4v[3];
#pragma unroll
      for (int o = 16; o > 0; o >>= 1) {  // 32 threads share row gm (one wave half)
        pv0 += __shfl_xor(pv0, o);
        pv1 += __shfl_xor(pv1, o);
      }
      if ((tid & 31) == 0) {
        float2 pr = {pv0, pv1};
        *(float2*)&vpart[(size_t)(bn * 1024 + gm) * 2] = pr;
      }
    }
  }
}

// --- the persistent 50-step kernel ------------------------------------------
__global__ __launch_bounds__(512, 2) void persist(
    const float* __restrict__ x0, const float* __restrict__ base,
    const float* __restrict__ tvec, const float* __restrict__ W0,
    const float* __restrict__ b1, const float* __restrict__ b2,
    const float* __restrict__ b3, const float* __restrict__ b4,
    const float* __restrict__ W4,
    const u16* __restrict__ w1t, const u16* __restrict__ w2t,
    const u16* __restrict__ w3t,
    u16* __restrict__ hA, u16* __restrict__ hB, u16* __restrict__ hC,
    float* __restrict__ vpart, float* __restrict__ xping,
    unsigned int* __restrict__ bar, float* __restrict__ xout) {
  __shared__ float red[8][16][68];  // 34,816 B
  const int tid = threadIdx.x;
  const int w = tid >> 6, lane = tid & 63;
  const int bn = blockIdx.x, bm = blockIdx.y;
  unsigned int phase = 0;

#pragma unroll 1
  for (int s = 0; s < NSTEP; ++s) {
    // ---- h0 phase: x(s) locally; write h0 tile [64 rows x 64 cols] -> hA ----
    {
      const int r = tid >> 3, c0 = (tid & 7) * 8;
      const int gr = bm * 64 + r;
      float xa, xb;
      if (s == 0) {
        xa = x0[2 * gr];
        xb = x0[2 * gr + 1];
      } else {
        float va = b4[0], vb = b4[1];
#pragma unroll 4
        for (int j = 0; j < 16; ++j) {
          float2 pp = *(const float2*)&vpart[(size_t)(j * 1024 + gr) * 2];
          va += pp.x; vb += pp.y;
        }
        float2 xo = *(const float2*)&xping[((s - 1) & 1) * 2048 + 2 * gr];
        xa = xo.x + DT * va;
        xb = xo.y + DT * vb;
      }
      if (bn == 0 && (tid & 7) == 0) {
        float2 xn = {xa, xb};
        *(float2*)&xping[(s & 1) * 2048 + 2 * gr] = xn;
      }
      const int gc = bn * 64 + c0;
      const float* bp = &base[(size_t)gr * H + gc];
      const float* tp = &tvec[(size_t)s * H + gc];
      const float* wap = &W0[254 * H + gc];
      const float* wbp = &W0[255 * H + gc];
      u16x8 o;
#pragma unroll
      for (int jj = 0; jj < 2; ++jj) {
        f32x4 bs = *(const f32x4*)(bp + 4 * jj);
        f32x4 tv = *(const f32x4*)(tp + 4 * jj);
        f32x4 wa = *(const f32x4*)(wap + 4 * jj);
        f32x4 wb = *(const f32x4*)(wbp + 4 * jj);
#pragma unroll
        for (int e = 0; e < 4; ++e)
          o[4 * jj + e] = f2bf(silu(bs[e] + tv[e] + xa * wa[e] + xb * wb[e]));
      }
      *(u16x8*)&hA[(size_t)gr * H + gc] = o;
    }
    gsync(bar, ++phase);

    layer_phase<0>(hA, w1t, b1, hB, nullptr, nullptr, bn, bm, w, lane, tid, red);
    gsync(bar, ++phase);
    layer_phase<0>(hB, w2t, b2, hC, nullptr, nullptr, bn, bm, w, lane, tid, red);
    gsync(bar, ++phase);
    layer_phase<1>(hC, w3t, b3, nullptr, W4, vpart, bn, bm, w, lane, tid, red);
    gsync(bar, ++phase);
  }

  // ---- final: x(50) = x(49) + dt*(v(49)+b4) -> xout ----
  if (bn == 0 && (tid & 7) == 0) {
    const int gr = bm * 64 + (tid >> 3);
    float va = b4[0], vb = b4[1];
#pragma unroll 4
    for (int j = 0; j < 16; ++j) {
      float2 pp = *(const float2*)&vpart[(size_t)(j * 1024 + gr) * 2];
      va += pp.x; vb += pp.y;
    }
    float2 xo = *(const float2*)&xping[2048 + 2 * gr];  // (49&1)=1
    xout[2 * gr] = xo.x + DT * va;
    xout[2 * gr + 1] = xo.y + DT * vb;
  }
}

extern "C" void kernel_launch(void* const* d_in, const int* in_sizes, int n_in,
                              void* d_out, int out_size, void* d_ws, size_t ws_size,
                              hipStream_t stream) {
  const float* state = (const float*)d_in[0];
  const float* x0    = (const float*)d_in[1];
  const float* W0    = (const float*)d_in[2];
  const float* b0    = (const float*)d_in[3];
  const float* W1    = (const float*)d_in[4];
  const float* b1    = (const float*)d_in[5];
  const float* W2    = (const float*)d_in[6];
  const float* b2    = (const float*)d_in[7];
  const float* W3    = (const float*)d_in[8];
  const float* b3    = (const float*)d_in[9];
  const float* W4    = (const float*)d_in[10];
  const float* b4    = (const float*)d_in[11];
  float* xout = (float*)d_out;

  char* ws = (char*)d_ws;
  const size_t MB = 1024 * 1024;
  const size_t KB = 1024;
  float* base = (float*)(ws + 0);                     // 4 MiB
  float* tvec = (float*)(ws + 4 * MB);                // 200 KiB (256 reserved)
  u16* w1t = (u16*)(ws + 4 * MB + 256 * KB);          // 2 MiB each
  u16* w2t = (u16*)(ws + 6 * MB + 256 * KB);
  u16* w3t = (u16*)(ws + 8 * MB + 256 * KB);
  u16* hA  = (u16*)(ws + 10 * MB + 256 * KB);
  u16* hB  = (u16*)(ws + 12 * MB + 256 * KB);
  u16* hC  = (u16*)(ws + 14 * MB + 256 * KB);
  float* vpart = (float*)(ws + 16 * MB + 256 * KB);   // 128 KiB
  float* xping = (float*)(ws + 16 * MB + 384 * KB);   // 16 KiB
  unsigned int* bar = (unsigned int*)(ws + 16 * MB + 400 * KB);  // 4 KiB

  transpose_w<<<dim3(32, 32, 3), 256, 0, stream>>>(W1, W2, W3, w1t, w2t, w3t);
  base_gemm<<<dim3(16, 16), 256, 0, stream>>>(state, W0, b0, base);
  tvec_kernel<<<dim3(NSTEP, 4), 256, 0, stream>>>(W0, tvec);
  bar_init<<<1, 256, 0, stream>>>(bar);

  persist<<<dim3(16, 16), 512, 0, stream>>>(x0, base, tvec, W0, b1, b2, b3, b4,
                                            W4, w1t, w2t, w3t, hA, hB, hC,
                                            vpart, xping, bar, xout);
}

// Round 5
// 4923.021 us; speedup vs baseline: 1.4304x; 1.4304x over previous
//
#include <hip/hip_runtime.h>

// ---------------------------------------------------------------------------
// FlowMatchingShield: 50-step Euler sampler over a 5-layer MLP.
//   h = concat([state(254), x(2), temb(64)])  -> 320
//   h @ W0 split:  base = state@W0[0:254]+b0  (once)
//                  tvec[s] = temb(s)@W0[256:320] (once, 50 vectors)
//                  x-part = x@W0[254:256]  (elementwise per step)
//
// Round 5: persistent kernel, COHERENCE-MINIMAL sync. Round 4's counters
// (FETCH 4.4GB, 713 GB/s, 7ms) showed the acquire-polling barrier invalidated
// L2 continuously, refetching weights every phase. Fixes:
//  - barrier arrival = RELEASE fetch_add (buffer_wbl2 writeback, NO invalidate)
//  - poll = RELAXED; no acquire fence anywhere
//  - cross-block data (hB/hC/vpart) read via agent-scope relaxed atomic loads
//    (global_load sc0 sc1: bypass L1/L2, compiler-tracked waitcnt)
//  - weights/base/tvec/W0 use normal cached loads -> L2-resident all 50 steps
//  - h0 fused into L1 phase (A-frags built in-register): 3 barriers/step, no hA
//  - next layer's weight frags prefetched into registers BEFORE the barrier
//  - XCD swizzle: XCD k owns bm {2k,2k+1} (A-slab L2-locality)
// ---------------------------------------------------------------------------

typedef __bf16 bf16x8 __attribute__((ext_vector_type(8)));
typedef float  f32x4  __attribute__((ext_vector_type(4)));
typedef float  f32x2  __attribute__((ext_vector_type(2)));
typedef unsigned short u16;
typedef unsigned long long u64;
typedef u16 u16x8 __attribute__((ext_vector_type(8)));
typedef u16 u16x4 __attribute__((ext_vector_type(4)));
typedef u16 u16x2 __attribute__((ext_vector_type(2)));

#define H 1024
#define BATCH 1024
#define SDIM 254
#define NSTEP 50
#define DT 0.02f

__device__ __forceinline__ u16 f2bf(float f) {
  unsigned int u = __float_as_uint(f);
  return (u16)((u + 0x7FFFu + ((u >> 16) & 1u)) >> 16);
}

__device__ __forceinline__ float silu(float v) {
  return v / (1.0f + __expf(-v));
}

// --- one-time: W[k][n] fp32 -> WT[n][k] bf16, for W1..W3 (blockIdx.z picks) --
__global__ void transpose_w(const float* __restrict__ A, const float* __restrict__ B,
                            const float* __restrict__ C, u16* __restrict__ TA,
                            u16* __restrict__ TB, u16* __restrict__ TC) {
  const float* W = (blockIdx.z == 0) ? A : (blockIdx.z == 1) ? B : C;
  u16* T = (blockIdx.z == 0) ? TA : (blockIdx.z == 1) ? TB : TC;
  __shared__ float tile[32][33];
  const int n0 = blockIdx.x * 32, k0 = blockIdx.y * 32;
  const int tx = threadIdx.x & 31, ty = threadIdx.x >> 5;  // 32 x 8
#pragma unroll
  for (int i = 0; i < 4; ++i)
    tile[ty + 8 * i][tx] = W[(k0 + ty + 8 * i) * H + n0 + tx];
  __syncthreads();
#pragma unroll
  for (int i = 0; i < 4; ++i)
    T[(size_t)(n0 + ty + 8 * i) * H + k0 + tx] = f2bf(tile[tx][ty + 8 * i]);
}

// --- one-time: base[b][n] = b0[n] + sum_k state[b][k]*W0[k][n] (k<254) -------
__global__ __launch_bounds__(256) void base_gemm(const float* __restrict__ state,
                                                 const float* __restrict__ W0,
                                                 const float* __restrict__ b0,
                                                 float* __restrict__ base) {
  __shared__ float Sst[64][68];
  __shared__ float Wl[64][68];
  const int bc = blockIdx.x, br = blockIdx.y, tid = threadIdx.x;
  const int myrow = (tid >> 4) * 4;
  const int mycol = (tid & 15) * 4;
  const int lr = tid >> 2;
  const int lc = (tid & 3) * 16;
  f32x4 acc[4] = {};

  for (int kc = 0; kc < 4; ++kc) {
    const int k0 = kc * 64;
#pragma unroll
    for (int j = 0; j < 8; ++j) {
      const int k = k0 + lc + 2 * j;
      float vx = 0.f, vy = 0.f;
      if (k + 1 < SDIM) {
        float2 v = *(const float2*)&state[(size_t)(br * 64 + lr) * SDIM + k];
        vx = v.x; vy = v.y;
      } else if (k < SDIM) {
        vx = state[(size_t)(br * 64 + lr) * SDIM + k];
      }
      Sst[lr][lc + 2 * j] = vx;
      Sst[lr][lc + 2 * j + 1] = vy;
    }
#pragma unroll
    for (int j = 0; j < 4; ++j) {
      f32x4 wv = {};
      if (k0 + lr < SDIM)
        wv = *(const f32x4*)&W0[(size_t)(k0 + lr) * H + bc * 64 + lc + 4 * j];
      *(f32x4*)&Wl[lr][lc + 4 * j] = wv;
    }
    __syncthreads();
#pragma unroll 4
    for (int kk = 0; kk < 64; kk += 4) {
      f32x4 sv[4], wv[4];
#pragma unroll
      for (int r = 0; r < 4; ++r) sv[r] = *(const f32x4*)&Sst[myrow + r][kk];
#pragma unroll
      for (int j = 0; j < 4; ++j) wv[j] = *(const f32x4*)&Wl[kk + j][mycol];
#pragma unroll
      for (int r = 0; r < 4; ++r)
#pragma unroll
        for (int j = 0; j < 4; ++j)
          acc[r] += sv[r][j] * wv[j];
    }
    __syncthreads();
  }

  const f32x4 bv = *(const f32x4*)&b0[bc * 64 + mycol];
#pragma unroll
  for (int r = 0; r < 4; ++r) {
    f32x4 o = acc[r] + bv;
    *(f32x4*)&base[(size_t)(br * 64 + myrow + r) * H + bc * 64 + mycol] = o;
  }
}

// --- one-time: tvec[s][h] = sum_j sin(t fj) W0[256+j][h] + cos(t fj) W0[288+j][h]
__global__ void tvec_kernel(const float* __restrict__ W0, float* __restrict__ tvec) {
  const int s = blockIdx.x;
  const int h = blockIdx.y * 256 + threadIdx.x;
  const float t = (float)s * DT;
  float acc = 0.0f;
#pragma unroll
  for (int j = 0; j < 32; ++j) {
    float fr = __expf((float)j * (-9.210340371976184f / 31.0f));
    float ang = t * fr;
    acc += __sinf(ang) * W0[(256 + j) * H + h] + __cosf(ang) * W0[(288 + j) * H + h];
  }
  tvec[s * H + h] = acc;
}

// --- one-time: zero the grid-barrier counters (ws is poisoned each call) ----
__global__ void bar_init(unsigned int* __restrict__ bar) {
  bar[threadIdx.x] = 0u;
  bar[threadIdx.x + 256] = 0u;
  bar[threadIdx.x + 512] = 0u;
  bar[threadIdx.x + 768] = 0u;
}

// --- grid barrier, coherence-minimal: release-add arrival (wbl2 writeback,
// no invalidate), relaxed root+flag, RELAXED polling, no acquire anywhere.
__device__ __forceinline__ void gsync(unsigned int* bar, unsigned int phase, int leaf) {
  __syncthreads();
  if (threadIdx.x == 0) {
    unsigned int v = __hip_atomic_fetch_add(bar + (leaf << 5), 1u, __ATOMIC_RELEASE,
                                            __HIP_MEMORY_SCOPE_AGENT);
    if (v == phase * 16u - 1u) {  // last of this 16-block leaf
      unsigned int r = __hip_atomic_fetch_add(bar + 512, 1u, __ATOMIC_RELAXED,
                                              __HIP_MEMORY_SCOPE_AGENT);
      if (r == phase * 16u - 1u)  // last leaf
        __hip_atomic_store(bar + 544, phase, __ATOMIC_RELAXED,
                           __HIP_MEMORY_SCOPE_AGENT);
    }
    while (__hip_atomic_load(bar + 544, __ATOMIC_RELAXED,
                             __HIP_MEMORY_SCOPE_AGENT) < phase)
      __builtin_amdgcn_s_sleep(4);
  }
  __syncthreads();
}

__device__ __forceinline__ void mfma_all(const bf16x8 (&fa)[4][4],
                                         const bf16x8 (&fb)[4][4],
                                         f32x4 (&acc)[4][4]) {
#pragma unroll
  for (int it = 0; it < 4; ++it)
#pragma unroll
    for (int mt = 0; mt < 4; ++mt)
#pragma unroll
      for (int nt = 0; nt < 4; ++nt)
        acc[mt][nt] = __builtin_amdgcn_mfma_f32_16x16x32_bf16(fa[it][mt], fb[it][nt],
                                                              acc[mt][nt], 0, 0, 0);
}

// normal cached loads (weights: immutable, L2-resident)
__device__ __forceinline__ void load_frags(bf16x8 (&f)[4][4], const u16* __restrict__ P) {
#pragma unroll
  for (int it = 0; it < 4; ++it)
#pragma unroll
    for (int q = 0; q < 4; ++q)
      f[it][q] = *(const bf16x8*)(P + q * 16 * H + it * 32);
}

// agent-coherent loads (activations written by other blocks this step)
__device__ __forceinline__ void load_frags_coherent(bf16x8 (&f)[4][4], const u16* P) {
#pragma unroll
  for (int it = 0; it < 4; ++it)
#pragma unroll
    for (int q = 0; q < 4; ++q) {
      const u64* p = (const u64*)(P + q * 16 * H + it * 32);
      union { bf16x8 v; u64 d[2]; } u;
      u.d[0] = __hip_atomic_load(p, __ATOMIC_RELAXED, __HIP_MEMORY_SCOPE_AGENT);
      u.d[1] = __hip_atomic_load(p + 1, __ATOMIC_RELAXED, __HIP_MEMORY_SCOPE_AGENT);
      f[it][q] = u.v;
    }
}

// cross-wave K-reduction + epilogue. TAIL=0: silu -> bf16 out. TAIL=1:
// silu -> .W4 -> 32-lane reduce -> vpart.
template <int TAIL>
__device__ __forceinline__ void reduce_store(f32x4 (&acc)[4][4],
                                             const float* __restrict__ bias,
                                             u16* __restrict__ outp,
                                             const float* __restrict__ W4,
                                             float* __restrict__ vpart,
                                             int bn, int bm, int w, int lane, int tid,
                                             float (*red)[16][68]) {
  const int lr = lane & 15, quad = lane >> 4;
  const int m = tid >> 5, n0 = (tid & 31) * 2;
  const f32x2 bv = *(const f32x2*)&bias[bn * 64 + n0];
  f32x4 w4v = {};
  if (TAIL) w4v = *(const f32x4*)&W4[2 * (bn * 64 + n0)];
#pragma unroll
  for (int p = 0; p < 4; ++p) {
    if (p) __syncthreads();  // WAR vs previous phase's reads
#pragma unroll
    for (int nt = 0; nt < 4; ++nt)
#pragma unroll
      for (int r = 0; r < 4; ++r)
        red[w][quad * 4 + r][nt * 16 + lr] = acc[p][nt][r];
    __syncthreads();
    f32x2 sv = {};
#pragma unroll
    for (int ww = 0; ww < 8; ++ww) sv += *(const f32x2*)&red[ww][m][n0];
    const int gm = bm * 64 + p * 16 + m;
    if (!TAIL) {
      u16x2 o = {f2bf(silu(sv[0] + bv[0])), f2bf(silu(sv[1] + bv[1]))};
      *(u16x2*)&outp[(size_t)gm * H + bn * 64 + n0] = o;
    } else {
      const float t0 = silu(sv[0] + bv[0]), t1 = silu(sv[1] + bv[1]);
      float pv0 = t0 * w4v[0] + t1 * w4v[2];
      float pv1 = t0 * w4v[1] + t1 * w4v[3];
#pragma unroll
      for (int o = 16; o > 0; o >>= 1) {
        pv0 += __shfl_xor(pv0, o);
        pv1 += __shfl_xor(pv1, o);
      }
      if ((tid & 31) == 0) {
        float2 pr = {pv0, pv1};
        *(float2*)&vpart[(size_t)(bn * 1024 + gm) * 2] = pr;
      }
    }
  }
}

// --- the persistent 50-step kernel ------------------------------------------
__global__ __launch_bounds__(512, 2) void persist(
    const float* __restrict__ x0, const float* __restrict__ base,
    const float* __restrict__ tvec, const float* __restrict__ W0,
    const float* __restrict__ b1, const float* __restrict__ b2,
    const float* __restrict__ b3, const float* __restrict__ b4,
    const float* __restrict__ W4,
    const u16* __restrict__ w1t, const u16* __restrict__ w2t,
    const u16* __restrict__ w3t,
    u16* __restrict__ hB, u16* __restrict__ hC,
    float* __restrict__ vpart, unsigned int* __restrict__ bar,
    float* __restrict__ xout) {
  __shared__ float red[8][16][68];  // 34,816 B
  __shared__ float2 xv[64];         // this bm-slab's x, persistent across steps
  const int tid = threadIdx.x;
  const int w = tid >> 6, lane = tid & 63;
  const int lr = lane & 15, quad = lane >> 4;
  // XCD swizzle: XCD (fid&7) owns bm {2k, 2k+1}, all bn.
  const int fid = blockIdx.x;
  const int idx = fid >> 3;
  const int bm = ((fid & 7) << 1) | (idx & 1);
  const int bn = idx >> 1;
  const int leaf = fid & 15;
  unsigned int phase = 0;

  const u16* Bw1 = w1t + (size_t)(bn * 64 + lr) * H + w * 128 + quad * 8;
  const u16* Bw2 = w2t + (size_t)(bn * 64 + lr) * H + w * 128 + quad * 8;
  const u16* Bw3 = w3t + (size_t)(bn * 64 + lr) * H + w * 128 + quad * 8;
  const u16* ApB = hB + (size_t)(bm * 64 + lr) * H + w * 128 + quad * 8;
  const u16* ApC = hC + (size_t)(bm * 64 + lr) * H + w * 128 + quad * 8;

  bf16x8 fb[4][4];
  load_frags(fb, Bw1);  // prologue: W1 fragments (cached)

#pragma unroll 1
  for (int s = 0; s < NSTEP; ++s) {
    // ---- P1: x(s) update; h0 A-frags in-register; GEMM L1 -> hB ----
    if (tid < 64) {
      const int gr = bm * 64 + tid;
      float2 xc;
      if (s == 0) {
        xc = *(const float2*)&x0[2 * gr];
      } else {
        float va = b4[0], vb = b4[1];
#pragma unroll
        for (int j = 0; j < 16; ++j) {
          union { float2 f; u64 d; } u;
          u.d = __hip_atomic_load((const u64*)&vpart[(size_t)(j * 1024 + gr) * 2],
                                  __ATOMIC_RELAXED, __HIP_MEMORY_SCOPE_AGENT);
          va += u.f.x; vb += u.f.y;
        }
        xc = xv[tid];
        xc.x += DT * va;
        xc.y += DT * vb;
      }
      xv[tid] = xc;
    }
    __syncthreads();

    {
      bf16x8 fa[4][4];
      const int kb = w * 128 + quad * 8;
#pragma unroll
      for (int it = 0; it < 4; ++it) {
        const int k0 = kb + it * 32;
        const f32x4 tv0 = *(const f32x4*)&tvec[(size_t)s * H + k0];
        const f32x4 tv1 = *(const f32x4*)&tvec[(size_t)s * H + k0 + 4];
        const f32x4 wa0 = *(const f32x4*)&W0[254 * H + k0];
        const f32x4 wa1 = *(const f32x4*)&W0[254 * H + k0 + 4];
        const f32x4 wb0 = *(const f32x4*)&W0[255 * H + k0];
        const f32x4 wb1 = *(const f32x4*)&W0[255 * H + k0 + 4];
#pragma unroll
        for (int q = 0; q < 4; ++q) {
          const int r = lr + 16 * q;
          const float2 xc = xv[r];
          const float* bp = &base[(size_t)(bm * 64 + r) * H + k0];
          const f32x4 b0v = *(const f32x4*)bp;
          const f32x4 b1v = *(const f32x4*)(bp + 4);
          u16x8 o;
#pragma unroll
          for (int e = 0; e < 4; ++e)
            o[e] = f2bf(silu(b0v[e] + tv0[e] + xc.x * wa0[e] + xc.y * wb0[e]));
#pragma unroll
          for (int e = 0; e < 4; ++e)
            o[4 + e] = f2bf(silu(b1v[e] + tv1[e] + xc.x * wa1[e] + xc.y * wb1[e]));
          fa[it][q] = *(bf16x8*)&o;
        }
      }
      f32x4 acc[4][4] = {};
      mfma_all(fa, fb, acc);
      load_frags(fb, Bw2);  // prefetch W2 (cached; completes under barrier)
      reduce_store<0>(acc, b1, hB, nullptr, nullptr, bn, bm, w, lane, tid, red);
    }
    gsync(bar, ++phase, leaf);

    // ---- P2: L2 GEMM: hB (coherent) @ W2 -> hC ----
    {
      bf16x8 fa[4][4];
      load_frags_coherent(fa, ApB);
      f32x4 acc[4][4] = {};
      mfma_all(fa, fb, acc);
      load_frags(fb, Bw3);  // prefetch W3
      reduce_store<0>(acc, b2, hC, nullptr, nullptr, bn, bm, w, lane, tid, red);
    }
    gsync(bar, ++phase, leaf);

    // ---- P3: L3 GEMM + head: hC (coherent) @ W3 -> silu -> .W4 -> vpart ----
    {
      bf16x8 fa[4][4];
      load_frags_coherent(fa, ApC);
      f32x4 acc[4][4] = {};
      mfma_all(fa, fb, acc);
      load_frags(fb, Bw1);  // prefetch W1 for next step
      reduce_store<1>(acc, b3, nullptr, W4, vpart, bn, bm, w, lane, tid, red);
    }
    gsync(bar, ++phase, leaf);
  }

  // ---- final: x(50) = x(49) + dt*(v(49)+b4) -> xout ----
  if (bn == 0 && tid < 64) {
    const int gr = bm * 64 + tid;
    float va = b4[0], vb = b4[1];
#pragma unroll
    for (int j = 0; j < 16; ++j) {
      union { float2 f; u64 d; } u;
      u.d = __hip_atomic_load((const u64*)&vpart[(size_t)(j * 1024 + gr) * 2],
                              __ATOMIC_RELAXED, __HIP_MEMORY_SCOPE_AGENT);
      va += u.f.x; vb += u.f.y;
    }
    xout[2 * gr] = xv[tid].x + DT * va;
    xout[2 * gr + 1] = xv[tid].y + DT * vb;
  }
}

extern "C" void kernel_launch(void* const* d_in, const int* in_sizes, int n_in,
                              void* d_out, int out_size, void* d_ws, size_t ws_size,
                              hipStream_t stream) {
  const float* state = (const float*)d_in[0];
  const float* x0    = (const float*)d_in[1];
  const float* W0    = (const float*)d_in[2];
  const float* b0    = (const float*)d_in[3];
  const float* W1    = (const float*)d_in[4];
  const float* b1    = (const float*)d_in[5];
  const float* W2    = (const float*)d_in[6];
  const float* b2    = (const float*)d_in[7];
  const float* W3    = (const float*)d_in[8];
  const float* b3    = (const float*)d_in[9];
  const float* W4    = (const float*)d_in[10];
  const float* b4    = (const float*)d_in[11];
  float* xout = (float*)d_out;

  char* ws = (char*)d_ws;
  const size_t MB = 1024 * 1024;
  const size_t KB = 1024;
  float* base = (float*)(ws + 0);                     // 4 MiB
  float* tvec = (float*)(ws + 4 * MB);                // 200 KiB (256 reserved)
  u16* w1t = (u16*)(ws + 4 * MB + 256 * KB);          // 2 MiB each
  u16* w2t = (u16*)(ws + 6 * MB + 256 * KB);
  u16* w3t = (u16*)(ws + 8 * MB + 256 * KB);
  u16* hB  = (u16*)(ws + 10 * MB + 256 * KB);
  u16* hC  = (u16*)(ws + 12 * MB + 256 * KB);
  float* vpart = (float*)(ws + 14 * MB + 256 * KB);   // 128 KiB
  unsigned int* bar = (unsigned int*)(ws + 14 * MB + 384 * KB);  // 4 KiB

  transpose_w<<<dim3(32, 32, 3), 256, 0, stream>>>(W1, W2, W3, w1t, w2t, w3t);
  base_gemm<<<dim3(16, 16), 256, 0, stream>>>(state, W0, b0, base);
  tvec_kernel<<<dim3(NSTEP, 4), 256, 0, stream>>>(W0, tvec);
  bar_init<<<1, 256, 0, stream>>>(bar);

  persist<<<dim3(256), 512, 0, stream>>>(x0, base, tvec, W0, b1, b2, b3, b4,
                                         W4, w1t, w2t, w3t, hB, hC,
                                         vpart, bar, xout);
}

// Round 6
// 4207.530 us; speedup vs baseline: 1.6737x; 1.1700x over previous
//
#include <hip/hip_runtime.h>

// ---------------------------------------------------------------------------
// FlowMatchingShield: 50-step Euler sampler over a 5-layer MLP.
// Round 6 (persistent v3). Round-5 counters: 120 MB/step fabric traffic =
// 48 MB weight L2-thrash (XCD held 6MB of weights vs 4MB L2) + 64 MB coherent
// activation reads issued as non-coalescing 8B atomics. Fixes:
//  - partition: XCD x owns 16 bm-slabs (rows, 32 each) x 2 bn-slices (cols,
//    128 each): weights 1.5MB + base 2MB per XCD -> L2-resident all 50 steps
//  - tiles 32x128 (grid 32bm x 8bn): A-read amplification 16x -> 8x
//  - coherent reads = inline-asm global_load_dwordx4 sc0 sc1 (plain loads,
//    coalesce normally) + batched s_waitcnt vmcnt(0) + sched_barrier(0)
//  - barrier: round-5 release-add / relaxed-poll gsync (proven correct)
// ---------------------------------------------------------------------------

typedef __bf16 bf16x8 __attribute__((ext_vector_type(8)));
typedef float  f32x4  __attribute__((ext_vector_type(4)));
typedef float  f32x2  __attribute__((ext_vector_type(2)));
typedef unsigned short u16;
typedef unsigned long long u64;
typedef u16 u16x8 __attribute__((ext_vector_type(8)));
typedef u16 u16x4 __attribute__((ext_vector_type(4)));
typedef u16 u16x2 __attribute__((ext_vector_type(2)));

#define H 1024
#define BATCH 1024
#define SDIM 254
#define NSTEP 50
#define DT 0.02f
#define BM 32   // rows per block
#define BN 128  // cols per block

__device__ __forceinline__ u16 f2bf(float f) {
  unsigned int u = __float_as_uint(f);
  return (u16)((u + 0x7FFFu + ((u >> 16) & 1u)) >> 16);
}

__device__ __forceinline__ float silu(float v) {
  return v / (1.0f + __expf(-v));
}

// coherent 16B load: bypass L1/L2, read LLC (coalesces like a normal load)
__device__ __forceinline__ bf16x8 cload(const u16* p) {
  bf16x8 r;
  asm volatile("global_load_dwordx4 %0, %1, off sc0 sc1" : "=v"(r) : "v"(p));
  return r;
}
__device__ __forceinline__ void cwait() {
  asm volatile("s_waitcnt vmcnt(0)" ::: "memory");
  __builtin_amdgcn_sched_barrier(0);  // rule 18: fence reg-only consumers
}

// --- one-time: W[k][n] fp32 -> WT[n][k] bf16, for W1..W3 (blockIdx.z picks) --
__global__ void transpose_w(const float* __restrict__ A, const float* __restrict__ B,
                            const float* __restrict__ C, u16* __restrict__ TA,
                            u16* __restrict__ TB, u16* __restrict__ TC) {
  const float* W = (blockIdx.z == 0) ? A : (blockIdx.z == 1) ? B : C;
  u16* T = (blockIdx.z == 0) ? TA : (blockIdx.z == 1) ? TB : TC;
  __shared__ float tile[32][33];
  const int n0 = blockIdx.x * 32, k0 = blockIdx.y * 32;
  const int tx = threadIdx.x & 31, ty = threadIdx.x >> 5;  // 32 x 8
#pragma unroll
  for (int i = 0; i < 4; ++i)
    tile[ty + 8 * i][tx] = W[(k0 + ty + 8 * i) * H + n0 + tx];
  __syncthreads();
#pragma unroll
  for (int i = 0; i < 4; ++i)
    T[(size_t)(n0 + ty + 8 * i) * H + k0 + tx] = f2bf(tile[tx][ty + 8 * i]);
}

// --- one-time: base[b][n] = b0[n] + sum_k state[b][k]*W0[k][n] (k<254) -------
__global__ __launch_bounds__(256) void base_gemm(const float* __restrict__ state,
                                                 const float* __restrict__ W0,
                                                 const float* __restrict__ b0,
                                                 float* __restrict__ base) {
  __shared__ float Sst[64][68];
  __shared__ float Wl[64][68];
  const int bc = blockIdx.x, br = blockIdx.y, tid = threadIdx.x;
  const int myrow = (tid >> 4) * 4;
  const int mycol = (tid & 15) * 4;
  const int lr = tid >> 2;
  const int lc = (tid & 3) * 16;
  f32x4 acc[4] = {};

  for (int kc = 0; kc < 4; ++kc) {
    const int k0 = kc * 64;
#pragma unroll
    for (int j = 0; j < 8; ++j) {
      const int k = k0 + lc + 2 * j;
      float vx = 0.f, vy = 0.f;
      if (k + 1 < SDIM) {
        float2 v = *(const float2*)&state[(size_t)(br * 64 + lr) * SDIM + k];
        vx = v.x; vy = v.y;
      } else if (k < SDIM) {
        vx = state[(size_t)(br * 64 + lr) * SDIM + k];
      }
      Sst[lr][lc + 2 * j] = vx;
      Sst[lr][lc + 2 * j + 1] = vy;
    }
#pragma unroll
    for (int j = 0; j < 4; ++j) {
      f32x4 wv = {};
      if (k0 + lr < SDIM)
        wv = *(const f32x4*)&W0[(size_t)(k0 + lr) * H + bc * 64 + lc + 4 * j];
      *(f32x4*)&Wl[lr][lc + 4 * j] = wv;
    }
    __syncthreads();
#pragma unroll 4
    for (int kk = 0; kk < 64; kk += 4) {
      f32x4 sv[4], wv[4];
#pragma unroll
      for (int r = 0; r < 4; ++r) sv[r] = *(const f32x4*)&Sst[myrow + r][kk];
#pragma unroll
      for (int j = 0; j < 4; ++j) wv[j] = *(const f32x4*)&Wl[kk + j][mycol];
#pragma unroll
      for (int r = 0; r < 4; ++r)
#pragma unroll
        for (int j = 0; j < 4; ++j)
          acc[r] += sv[r][j] * wv[j];
    }
    __syncthreads();
  }

  const f32x4 bv = *(const f32x4*)&b0[bc * 64 + mycol];
#pragma unroll
  for (int r = 0; r < 4; ++r) {
    f32x4 o = acc[r] + bv;
    *(f32x4*)&base[(size_t)(br * 64 + myrow + r) * H + bc * 64 + mycol] = o;
  }
}

// --- one-time: tvec[s][h] = sum_j sin(t fj) W0[256+j][h] + cos(t fj) W0[288+j][h]
__global__ void tvec_kernel(const float* __restrict__ W0, float* __restrict__ tvec) {
  const int s = blockIdx.x;
  const int h = blockIdx.y * 256 + threadIdx.x;
  const float t = (float)s * DT;
  float acc = 0.0f;
#pragma unroll
  for (int j = 0; j < 32; ++j) {
    float fr = __expf((float)j * (-9.210340371976184f / 31.0f));
    float ang = t * fr;
    acc += __sinf(ang) * W0[(256 + j) * H + h] + __cosf(ang) * W0[(288 + j) * H + h];
  }
  tvec[s * H + h] = acc;
}

// --- one-time: zero the grid-barrier counters (ws is poisoned each call) ----
__global__ void bar_init(unsigned int* __restrict__ bar) {
  bar[threadIdx.x] = 0u;
  bar[threadIdx.x + 256] = 0u;
  bar[threadIdx.x + 512] = 0u;
  bar[threadIdx.x + 768] = 0u;
}

// --- grid barrier: release-add arrival (wbl2 writeback, no invalidate),
// relaxed root+flag, RELAXED polling, no acquire anywhere.
__device__ __forceinline__ void gsync(unsigned int* bar, unsigned int phase, int leaf) {
  __syncthreads();
  if (threadIdx.x == 0) {
    unsigned int v = __hip_atomic_fetch_add(bar + (leaf << 5), 1u, __ATOMIC_RELEASE,
                                            __HIP_MEMORY_SCOPE_AGENT);
    if (v == phase * 16u - 1u) {  // last of this 16-block leaf
      unsigned int r = __hip_atomic_fetch_add(bar + 512, 1u, __ATOMIC_RELAXED,
                                              __HIP_MEMORY_SCOPE_AGENT);
      if (r == phase * 16u - 1u)  // last leaf
        __hip_atomic_store(bar + 544, phase, __ATOMIC_RELAXED,
                           __HIP_MEMORY_SCOPE_AGENT);
    }
    while (__hip_atomic_load(bar + 544, __ATOMIC_RELAXED,
                             __HIP_MEMORY_SCOPE_AGENT) < phase)
      __builtin_amdgcn_s_sleep(4);
  }
  __syncthreads();
}

// --- GEMM compute + cross-wave K-reduction + epilogue for one 32x128 tile ----
// fa: A-fragments already in registers. Weights via normal cached loads.
// TAIL=0: silu -> bf16 out. TAIL=1: silu -> .W4 -> wave reduce -> vpart.
template <int TAIL>
__device__ __forceinline__ void mfma_reduce(bf16x8 (&fa)[2][4],
                                            const u16* __restrict__ Bt,
                                            const float* __restrict__ bias,
                                            u16* __restrict__ outp,
                                            const float* __restrict__ W4,
                                            float* __restrict__ vpart,
                                            int bm, int bn, int w, int lane, int tid,
                                            float (*red)[8][132]) {
  const int lr = lane & 15, quad = lane >> 4;
  const u16* Bp = Bt + (size_t)(bn * BN + lr) * H + w * 128 + quad * 8;

  f32x4 acc[2][8] = {};
  bf16x8 fb[2][8];
#pragma unroll
  for (int q = 0; q < 8; ++q) fb[0][q] = *(const bf16x8*)(Bp + q * 16 * H);
#pragma unroll
  for (int it = 0; it < 4; ++it) {
    if (it < 3) {
#pragma unroll
      for (int q = 0; q < 8; ++q)
        fb[(it + 1) & 1][q] = *(const bf16x8*)(Bp + q * 16 * H + (it + 1) * 32);
    }
#pragma unroll
    for (int mt = 0; mt < 2; ++mt)
#pragma unroll
      for (int nt = 0; nt < 8; ++nt)
        acc[mt][nt] = __builtin_amdgcn_mfma_f32_16x16x32_bf16(fa[mt][it], fb[it & 1][nt],
                                                              acc[mt][nt], 0, 0, 0);
  }

  // cross-wave K-reduction: 4 phases of 8 rows
  const int m8 = tid >> 6;        // 0..7: row within phase (== wave index)
  const int c0 = (tid & 63) * 2;  // 0..126
  const f32x2 bv = *(const f32x2*)&bias[bn * BN + c0];
  f32x4 w4v = {};
  if (TAIL) w4v = *(const f32x4*)&W4[2 * (bn * BN + c0)];
#pragma unroll
  for (int p = 0; p < 4; ++p) {
    if (p) __syncthreads();  // WAR vs previous phase's reads
    const int mt = p >> 1, rh = p & 1;
    if ((quad >> 1) == rh) {
#pragma unroll
      for (int nt = 0; nt < 8; ++nt)
#pragma unroll
        for (int r = 0; r < 4; ++r)
          red[w][(quad & 1) * 4 + r][nt * 16 + lr] = acc[mt][nt][r];
    }
    __syncthreads();
    f32x2 sv = {};
#pragma unroll
    for (int ww = 0; ww < 8; ++ww) sv += *(const f32x2*)&red[ww][m8][c0];
    const int grow = bm * BM + p * 8 + m8;
    if (!TAIL) {
      u16x2 o = {f2bf(silu(sv[0] + bv[0])), f2bf(silu(sv[1] + bv[1]))};
      *(u16x2*)&outp[(size_t)grow * H + bn * BN + c0] = o;
    } else {
      const float t0 = silu(sv[0] + bv[0]), t1 = silu(sv[1] + bv[1]);
      float pv0 = t0 * w4v[0] + t1 * w4v[2];
      float pv1 = t0 * w4v[1] + t1 * w4v[3];
#pragma unroll
      for (int o = 32; o > 0; o >>= 1) {
        pv0 += __shfl_xor(pv0, o);
        pv1 += __shfl_xor(pv1, o);
      }
      if (lane == 0) {
        float2 pr = {pv0, pv1};
        *(float2*)&vpart[(size_t)(bn * 1024 + grow) * 2] = pr;
      }
    }
  }
}

// --- the persistent 50-step kernel ------------------------------------------
__global__ __launch_bounds__(512, 2) void persist(
    const float* __restrict__ x0, const float* __restrict__ base,
    const float* __restrict__ tvec, const float* __restrict__ W0,
    const float* __restrict__ b1, const float* __restrict__ b2,
    const float* __restrict__ b3, const float* __restrict__ b4,
    const float* __restrict__ W4,
    const u16* __restrict__ w1t, const u16* __restrict__ w2t,
    const u16* __restrict__ w3t,
    u16* __restrict__ hB, u16* __restrict__ hC,
    float* __restrict__ vpart, unsigned int* __restrict__ bar,
    float* __restrict__ xout) {
  __shared__ float red[8][8][132];  // 33.8 KB
  __shared__ float2 xv[BM];
  const int tid = threadIdx.x;
  const int w = tid >> 6, lane = tid & 63;
  const int lr = lane & 15, quad = lane >> 4;
  // XCD partition (perf heuristic only): xcd = fid&7 under round-robin.
  // XCD x owns bm-slabs [(x>>2)*16 .. +16) and bn-slices [(x&3)*2 .. +2):
  // weights 1.5MB + base 2MB per XCD -> fits 4MB L2, resident all steps.
  const int fid = blockIdx.x;
  const int xcd = fid & 7, idx = fid >> 3;
  const int bm = (xcd >> 2) * 16 + (idx >> 1);  // 0..31
  const int bn = (xcd & 3) * 2 + (idx & 1);     // 0..7
  const int leaf = fid & 15;
  unsigned int phase = 0;

  const u16* ApB = hB + (size_t)(bm * BM + lr) * H + w * 128 + quad * 8;
  const u16* ApC = hC + (size_t)(bm * BM + lr) * H + w * 128 + quad * 8;

#pragma unroll 1
  for (int s = 0; s < NSTEP; ++s) {
    // ---- P1: x(s) update; h0 A-frags built in-register; GEMM L1 -> hB ----
    if (tid < BM) {
      const int gr = bm * BM + tid;
      float2 xc;
      if (s == 0) {
        xc = *(const float2*)&x0[2 * gr];
      } else {
        float va = b4[0], vb = b4[1];
#pragma unroll
        for (int j = 0; j < 8; ++j) {
          union { float2 f; u64 d; } u;
          u.d = __hip_atomic_load((const u64*)&vpart[(size_t)(j * 1024 + gr) * 2],
                                  __ATOMIC_RELAXED, __HIP_MEMORY_SCOPE_AGENT);
          va += u.f.x; vb += u.f.y;
        }
        xc = xv[tid];
        xc.x += DT * va;
        xc.y += DT * vb;
      }
      xv[tid] = xc;
    }
    __syncthreads();

    {
      bf16x8 fa[2][4];
      const int kb = w * 128 + quad * 8;
#pragma unroll
      for (int it = 0; it < 4; ++it) {
        const int k0 = kb + it * 32;
        const f32x4 tv0 = *(const f32x4*)&tvec[(size_t)s * H + k0];
        const f32x4 tv1 = *(const f32x4*)&tvec[(size_t)s * H + k0 + 4];
        const f32x4 wa0 = *(const f32x4*)&W0[254 * H + k0];
        const f32x4 wa1 = *(const f32x4*)&W0[254 * H + k0 + 4];
        const f32x4 wb0 = *(const f32x4*)&W0[255 * H + k0];
        const f32x4 wb1 = *(const f32x4*)&W0[255 * H + k0 + 4];
#pragma unroll
        for (int mt = 0; mt < 2; ++mt) {
          const int r = mt * 16 + lr;
          const float2 xc = xv[r];
          const float* bp = &base[(size_t)(bm * BM + r) * H + k0];
          const f32x4 b0v = *(const f32x4*)bp;
          const f32x4 b1v = *(const f32x4*)(bp + 4);
          u16x8 o;
#pragma unroll
          for (int e = 0; e < 4; ++e)
            o[e] = f2bf(silu(b0v[e] + tv0[e] + xc.x * wa0[e] + xc.y * wb0[e]));
#pragma unroll
          for (int e = 0; e < 4; ++e)
            o[4 + e] = f2bf(silu(b1v[e] + tv1[e] + xc.x * wa1[e] + xc.y * wb1[e]));
          fa[mt][it] = *(bf16x8*)&o;
        }
      }
      mfma_reduce<0>(fa, w1t, b1, hB, nullptr, nullptr, bm, bn, w, lane, tid, red);
    }
    gsync(bar, ++phase, leaf);

    // ---- P2: L2 GEMM: hB (coherent dwordx4) @ W2 -> hC ----
    {
      bf16x8 fa[2][4];
#pragma unroll
      for (int mt = 0; mt < 2; ++mt)
#pragma unroll
        for (int it = 0; it < 4; ++it)
          fa[mt][it] = cload(ApB + mt * 16 * H + it * 32);
      cwait();
      mfma_reduce<0>(fa, w2t, b2, hC, nullptr, nullptr, bm, bn, w, lane, tid, red);
    }
    gsync(bar, ++phase, leaf);

    // ---- P3: L3 GEMM + head: hC (coherent) @ W3 -> silu -> .W4 -> vpart ----
    {
      bf16x8 fa[2][4];
#pragma unroll
      for (int mt = 0; mt < 2; ++mt)
#pragma unroll
        for (int it = 0; it < 4; ++it)
          fa[mt][it] = cload(ApC + mt * 16 * H + it * 32);
      cwait();
      mfma_reduce<1>(fa, w3t, b3, nullptr, W4, vpart, bm, bn, w, lane, tid, red);
    }
    gsync(bar, ++phase, leaf);
  }

  // ---- final: x(50) = x(49) + dt*(v(49)+b4) -> xout ----
  if (bn == 0 && tid < BM) {
    const int gr = bm * BM + tid;
    float va = b4[0], vb = b4[1];
#pragma unroll
    for (int j = 0; j < 8; ++j) {
      union { float2 f; u64 d; } u;
      u.d = __hip_atomic_load((const u64*)&vpart[(size_t)(j * 1024 + gr) * 2],
                              __ATOMIC_RELAXED, __HIP_MEMORY_SCOPE_AGENT);
      va += u.f.x; vb += u.f.y;
    }
    xout[2 * gr] = xv[tid].x + DT * va;
    xout[2 * gr + 1] = xv[tid].y + DT * vb;
  }
}

extern "C" void kernel_launch(void* const* d_in, const int* in_sizes, int n_in,
                              void* d_out, int out_size, void* d_ws, size_t ws_size,
                              hipStream_t stream) {
  const float* state = (const float*)d_in[0];
  const float* x0    = (const float*)d_in[1];
  const float* W0    = (const float*)d_in[2];
  const float* b0    = (const float*)d_in[3];
  const float* W1    = (const float*)d_in[4];
  const float* b1    = (const float*)d_in[5];
  const float* W2    = (const float*)d_in[6];
  const float* b2    = (const float*)d_in[7];
  const float* W3    = (const float*)d_in[8];
  const float* b3    = (const float*)d_in[9];
  const float* W4    = (const float*)d_in[10];
  const float* b4    = (const float*)d_in[11];
  float* xout = (float*)d_out;

  char* ws = (char*)d_ws;
  const size_t MB = 1024 * 1024;
  const size_t KB = 1024;
  float* base = (float*)(ws + 0);                     // 4 MiB
  float* tvec = (float*)(ws + 4 * MB);                // 200 KiB (256 reserved)
  u16* w1t = (u16*)(ws + 4 * MB + 256 * KB);          // 2 MiB each
  u16* w2t = (u16*)(ws + 6 * MB + 256 * KB);
  u16* w3t = (u16*)(ws + 8 * MB + 256 * KB);
  u16* hB  = (u16*)(ws + 10 * MB + 256 * KB);
  u16* hC  = (u16*)(ws + 12 * MB + 256 * KB);
  float* vpart = (float*)(ws + 14 * MB + 256 * KB);   // 64 KiB (128 reserved)
  unsigned int* bar = (unsigned int*)(ws + 14 * MB + 384 * KB);  // 4 KiB

  transpose_w<<<dim3(32, 32, 3), 256, 0, stream>>>(W1, W2, W3, w1t, w2t, w3t);
  base_gemm<<<dim3(16, 16), 256, 0, stream>>>(state, W0, b0, base);
  tvec_kernel<<<dim3(NSTEP, 4), 256, 0, stream>>>(W0, tvec);
  bar_init<<<1, 256, 0, stream>>>(bar);

  persist<<<dim3(256), 512, 0, stream>>>(x0, base, tvec, W0, b1, b2, b3, b4,
                                         W4, w1t, w2t, w3t, hB, hC,
                                         vpart, bar, xout);
}

// Round 7
// 2271.212 us; speedup vs baseline: 3.1006x; 1.8525x over previous
//
#include <hip/hip_runtime.h>

// ---------------------------------------------------------------------------
// FlowMatchingShield: 50-step Euler sampler over a 5-layer MLP.
// Round 7: REVERT to multi-dispatch (persistent path falsified: rounds 4-6
// measured 85-95us/step fabric-bound vs 36us/step multi-dispatch; two
// different L2-residency schemes failed to reduce FETCH). Attack the measured
// bottleneck instead: dispatch count. 204 -> 154 dispatches:
//   per step: L1 (h0-build fused in-register, reads bf16 base/tvec/wx)
//             L2 (plain GEMM; also zeroes vacc[s&1])
//             L3 (GEMM + silu + W4-dot partials -> atomicAdd vacc[s&1])
//   x recomputed per block from xcur[(s-1)&1] + vacc[(s-1)&1] (double-
//   buffered, so concurrent blocks never read a buffer being written).
// GEMM core + reduction epilogue = verified round-2/4 code (absmax 0.0156).
// ---------------------------------------------------------------------------

typedef __bf16 bf16x8 __attribute__((ext_vector_type(8)));
typedef float  f32x4  __attribute__((ext_vector_type(4)));
typedef float  f32x2  __attribute__((ext_vector_type(2)));
typedef unsigned short u16;
typedef u16 u16x8 __attribute__((ext_vector_type(8)));
typedef u16 u16x4 __attribute__((ext_vector_type(4)));
typedef u16 u16x2 __attribute__((ext_vector_type(2)));

#define H 1024
#define BATCH 1024
#define SDIM 254
#define NSTEP 50
#define DT 0.02f

__device__ __forceinline__ u16 f2bf(float f) {
  unsigned int u = __float_as_uint(f);
  return (u16)((u + 0x7FFFu + ((u >> 16) & 1u)) >> 16);
}

__device__ __forceinline__ float silu(float v) {
  return v / (1.0f + __expf(-v));
}

// --- one-time: W[k][n] fp32 -> WT[n][k] bf16, for W1..W3 (blockIdx.z picks) --
__global__ void transpose_w(const float* __restrict__ A, const float* __restrict__ B,
                            const float* __restrict__ C, u16* __restrict__ TA,
                            u16* __restrict__ TB, u16* __restrict__ TC) {
  const float* W = (blockIdx.z == 0) ? A : (blockIdx.z == 1) ? B : C;
  u16* T = (blockIdx.z == 0) ? TA : (blockIdx.z == 1) ? TB : TC;
  __shared__ float tile[32][33];
  const int n0 = blockIdx.x * 32, k0 = blockIdx.y * 32;
  const int tx = threadIdx.x & 31, ty = threadIdx.x >> 5;  // 32 x 8
#pragma unroll
  for (int i = 0; i < 4; ++i)
    tile[ty + 8 * i][tx] = W[(k0 + ty + 8 * i) * H + n0 + tx];
  __syncthreads();
#pragma unroll
  for (int i = 0; i < 4; ++i)
    T[(size_t)(n0 + ty + 8 * i) * H + k0 + tx] = f2bf(tile[tx][ty + 8 * i]);
}

// --- one-time: base16[b][n] = bf16(b0[n] + sum_k state[b][k]*W0[k][n]) ------
__global__ __launch_bounds__(256) void base_gemm(const float* __restrict__ state,
                                                 const float* __restrict__ W0,
                                                 const float* __restrict__ b0,
                                                 u16* __restrict__ base16) {
  __shared__ float Sst[64][68];
  __shared__ float Wl[64][68];
  const int bc = blockIdx.x, br = blockIdx.y, tid = threadIdx.x;
  const int myrow = (tid >> 4) * 4;
  const int mycol = (tid & 15) * 4;
  const int lr = tid >> 2;
  const int lc = (tid & 3) * 16;
  f32x4 acc[4] = {};

  for (int kc = 0; kc < 4; ++kc) {
    const int k0 = kc * 64;
#pragma unroll
    for (int j = 0; j < 8; ++j) {
      const int k = k0 + lc + 2 * j;
      float vx = 0.f, vy = 0.f;
      if (k + 1 < SDIM) {
        float2 v = *(const float2*)&state[(size_t)(br * 64 + lr) * SDIM + k];
        vx = v.x; vy = v.y;
      } else if (k < SDIM) {
        vx = state[(size_t)(br * 64 + lr) * SDIM + k];
      }
      Sst[lr][lc + 2 * j] = vx;
      Sst[lr][lc + 2 * j + 1] = vy;
    }
#pragma unroll
    for (int j = 0; j < 4; ++j) {
      f32x4 wv = {};
      if (k0 + lr < SDIM)
        wv = *(const f32x4*)&W0[(size_t)(k0 + lr) * H + bc * 64 + lc + 4 * j];
      *(f32x4*)&Wl[lr][lc + 4 * j] = wv;
    }
    __syncthreads();
#pragma unroll 4
    for (int kk = 0; kk < 64; kk += 4) {
      f32x4 sv[4], wv[4];
#pragma unroll
      for (int r = 0; r < 4; ++r) sv[r] = *(const f32x4*)&Sst[myrow + r][kk];
#pragma unroll
      for (int j = 0; j < 4; ++j) wv[j] = *(const f32x4*)&Wl[kk + j][mycol];
#pragma unroll
      for (int r = 0; r < 4; ++r)
#pragma unroll
        for (int j = 0; j < 4; ++j)
          acc[r] += sv[r][j] * wv[j];
    }
    __syncthreads();
  }

  const f32x4 bv = *(const f32x4*)&b0[bc * 64 + mycol];
#pragma unroll
  for (int r = 0; r < 4; ++r) {
    u16x4 o;
#pragma unroll
    for (int e = 0; e < 4; ++e) o[e] = f2bf(acc[r][e] + bv[e]);
    *(u16x4*)&base16[(size_t)(br * 64 + myrow + r) * H + bc * 64 + mycol] = o;
  }
}

// --- one-time: tvecb[s][h] (bf16) for s<50; s==50 writes wxa/wxb = bf16 W0 rows
__global__ void tvec_kernel(const float* __restrict__ W0, u16* __restrict__ tvecb,
                            u16* __restrict__ wxa, u16* __restrict__ wxb) {
  const int s = blockIdx.x;
  const int h = blockIdx.y * 256 + threadIdx.x;
  if (s == NSTEP) {
    wxa[h] = f2bf(W0[254 * H + h]);
    wxb[h] = f2bf(W0[255 * H + h]);
    return;
  }
  const float t = (float)s * DT;
  float acc = 0.0f;
#pragma unroll
  for (int j = 0; j < 32; ++j) {
    float fr = __expf((float)j * (-9.210340371976184f / 31.0f));
    float ang = t * fr;
    acc += __sinf(ang) * W0[(256 + j) * H + h] + __cosf(ang) * W0[(288 + j) * H + h];
  }
  tvecb[s * H + h] = f2bf(acc);
}

// --- shared GEMM pieces (verified round-2/4 code) ---------------------------
__device__ __forceinline__ void mfma_all(const bf16x8 (&fa)[4][4],
                                         const bf16x8 (&fb)[4][4],
                                         f32x4 (&acc)[4][4]) {
#pragma unroll
  for (int it = 0; it < 4; ++it)
#pragma unroll
    for (int mt = 0; mt < 4; ++mt)
#pragma unroll
      for (int nt = 0; nt < 4; ++nt)
        acc[mt][nt] = __builtin_amdgcn_mfma_f32_16x16x32_bf16(fa[it][mt], fb[it][nt],
                                                              acc[mt][nt], 0, 0, 0);
}

__device__ __forceinline__ void load_frags(bf16x8 (&f)[4][4], const u16* __restrict__ P) {
#pragma unroll
  for (int it = 0; it < 4; ++it)
#pragma unroll
    for (int q = 0; q < 4; ++q)
      f[it][q] = *(const bf16x8*)(P + q * 16 * H + it * 32);
}

// cross-wave K-reduction + epilogue. TAIL=0: silu -> bf16 out.
// TAIL=1: silu -> .W4 -> 32-lane reduce -> atomicAdd vacc.
template <int TAIL>
__device__ __forceinline__ void reduce_epi(f32x4 (&acc)[4][4],
                                           const float* __restrict__ bias,
                                           u16* __restrict__ outp,
                                           const float* __restrict__ W4,
                                           float* __restrict__ vacc,
                                           int bn, int bm, int w, int lane, int tid,
                                           float (*red)[16][68]) {
  const int lr = lane & 15, quad = lane >> 4;
  const int m = tid >> 5, n0 = (tid & 31) * 2;
  const f32x2 bv = *(const f32x2*)&bias[bn * 64 + n0];
  f32x4 w4v = {};
  if (TAIL) w4v = *(const f32x4*)&W4[2 * (bn * 64 + n0)];
#pragma unroll
  for (int p = 0; p < 4; ++p) {
    if (p) __syncthreads();  // WAR vs previous phase's reads
#pragma unroll
    for (int nt = 0; nt < 4; ++nt)
#pragma unroll
      for (int r = 0; r < 4; ++r)
        red[w][quad * 4 + r][nt * 16 + lr] = acc[p][nt][r];
    __syncthreads();
    f32x2 sv = {};
#pragma unroll
    for (int ww = 0; ww < 8; ++ww) sv += *(const f32x2*)&red[ww][m][n0];
    const int gm = bm * 64 + p * 16 + m;
    if (!TAIL) {
      u16x2 o = {f2bf(silu(sv[0] + bv[0])), f2bf(silu(sv[1] + bv[1]))};
      *(u16x2*)&outp[(size_t)gm * H + bn * 64 + n0] = o;
    } else {
      const float t0 = silu(sv[0] + bv[0]), t1 = silu(sv[1] + bv[1]);
      float pv0 = t0 * w4v[0] + t1 * w4v[2];
      float pv1 = t0 * w4v[1] + t1 * w4v[3];
#pragma unroll
      for (int o = 16; o > 0; o >>= 1) {
        pv0 += __shfl_xor(pv0, o);
        pv1 += __shfl_xor(pv1, o);
      }
      if ((tid & 31) == 0) {
        atomicAdd(&vacc[2 * gm], pv0);
        atomicAdd(&vacc[2 * gm + 1], pv1);
      }
    }
  }
}

// --- L1: x-update + h0 A-frags built in-register + GEMM @W1 -> hB -----------
__global__ __launch_bounds__(512) void gemm_l1(
    const u16* __restrict__ base16, const u16* __restrict__ tvecb,
    const u16* __restrict__ wxa, const u16* __restrict__ wxb,
    const float* __restrict__ x0, const float* __restrict__ xrd,
    float* __restrict__ xwr, const float* __restrict__ vprev,
    const float* __restrict__ b4, const u16* __restrict__ w1t,
    const float* __restrict__ b1, u16* __restrict__ hB, int s) {
  __shared__ float red[8][16][68];
  __shared__ float2 xv[64];
  const int tid = threadIdx.x;
  const int w = tid >> 6, lane = tid & 63;
  const int lr = lane & 15, quad = lane >> 4;
  const int bn = blockIdx.x, bm = blockIdx.y;

  // issue B-fragment loads first: latency hides under the h0 VALU build
  const u16* Bp = w1t + (size_t)(bn * 64 + lr) * H + w * 128 + quad * 8;
  bf16x8 fb[4][4];
  load_frags(fb, Bp);

  if (tid < 64) {
    const int gr = bm * 64 + tid;
    float2 xc;
    if (s == 0) {
      xc = *(const float2*)&x0[2 * gr];
    } else {
      float2 xp = *(const float2*)&xrd[2 * gr];
      xc.x = xp.x + DT * (vprev[2 * gr] + b4[0]);
      xc.y = xp.y + DT * (vprev[2 * gr + 1] + b4[1]);
    }
    xv[tid] = xc;
    if (bn == 0) *(float2*)&xwr[2 * gr] = xc;  // other blocks read xrd only
  }
  __syncthreads();

  bf16x8 fa[4][4];
  const int kb = w * 128 + quad * 8;
#pragma unroll
  for (int it = 0; it < 4; ++it) {
    const int kq = kb + it * 32;
    const bf16x8 tv = *(const bf16x8*)&tvecb[(size_t)s * H + kq];
    const bf16x8 wa = *(const bf16x8*)&wxa[kq];
    const bf16x8 wb = *(const bf16x8*)&wxb[kq];
#pragma unroll
    for (int q = 0; q < 4; ++q) {
      const int r = lr + 16 * q;
      const bf16x8 bs = *(const bf16x8*)&base16[(size_t)(bm * 64 + r) * H + kq];
      const float2 xc = xv[r];
      u16x8 o;
#pragma unroll
      for (int e = 0; e < 8; ++e) {
        float v = (float)bs[e] + (float)tv[e] + xc.x * (float)wa[e] + xc.y * (float)wb[e];
        o[e] = f2bf(silu(v));
      }
      fa[it][q] = *(bf16x8*)&o;
    }
  }

  f32x4 acc[4][4] = {};
  mfma_all(fa, fb, acc);
  reduce_epi<0>(acc, b1, hB, nullptr, nullptr, bn, bm, w, lane, tid, red);
}

// --- L2: plain GEMM @W2 -> hC; also zeroes vacc[s&1] for L3 -----------------
__global__ __launch_bounds__(512, 2) void gemm_l2(
    const u16* __restrict__ A, const u16* __restrict__ BT,
    const float* __restrict__ bias, u16* __restrict__ out,
    float* __restrict__ vzero) {
  __shared__ float red[8][16][68];
  const int tid = threadIdx.x;
  const int w = tid >> 6, lane = tid & 63;
  const int lr = lane & 15, quad = lane >> 4;
  const int bn = blockIdx.x, bm = blockIdx.y;

  if (bn == 0 && tid < 128) vzero[bm * 128 + tid] = 0.0f;

  const u16* Ap = A + (size_t)(bm * 64 + lr) * H + w * 128 + quad * 8;
  const u16* Bp = BT + (size_t)(bn * 64 + lr) * H + w * 128 + quad * 8;
  bf16x8 fa[4][4], fb[4][4];
  load_frags(fa, Ap);
  load_frags(fb, Bp);
  f32x4 acc[4][4] = {};
  mfma_all(fa, fb, acc);
  reduce_epi<0>(acc, bias, out, nullptr, nullptr, bn, bm, w, lane, tid, red);
}

// --- L3: GEMM @W3 + silu + W4-head partials -> atomicAdd vacc[s&1] ----------
__global__ __launch_bounds__(512, 2) void gemm_l3(
    const u16* __restrict__ A, const u16* __restrict__ BT,
    const float* __restrict__ b3, const float* __restrict__ W4,
    float* __restrict__ vacc) {
  __shared__ float red[8][16][68];
  const int tid = threadIdx.x;
  const int w = tid >> 6, lane = tid & 63;
  const int lr = lane & 15, quad = lane >> 4;
  const int bn = blockIdx.x, bm = blockIdx.y;

  const u16* Ap = A + (size_t)(bm * 64 + lr) * H + w * 128 + quad * 8;
  const u16* Bp = BT + (size_t)(bn * 64 + lr) * H + w * 128 + quad * 8;
  bf16x8 fa[4][4], fb[4][4];
  load_frags(fa, Ap);
  load_frags(fb, Bp);
  f32x4 acc[4][4] = {};
  mfma_all(fa, fb, acc);
  reduce_epi<1>(acc, b3, nullptr, W4, vacc, bn, bm, w, lane, tid, red);
}

// --- final: x(50) = x(49) + dt*(v(49)+b4) -> xout ---------------------------
__global__ void final_x(const float* __restrict__ xcur1, const float* __restrict__ vacc1,
                        const float* __restrict__ b4, float* __restrict__ xout) {
  const int i = blockIdx.x * 256 + threadIdx.x;  // 0..2047
  xout[i] = xcur1[i] + DT * (vacc1[i] + b4[i & 1]);
}

extern "C" void kernel_launch(void* const* d_in, const int* in_sizes, int n_in,
                              void* d_out, int out_size, void* d_ws, size_t ws_size,
                              hipStream_t stream) {
  const float* state = (const float*)d_in[0];
  const float* x0    = (const float*)d_in[1];
  const float* W0    = (const float*)d_in[2];
  const float* b0    = (const float*)d_in[3];
  const float* W1    = (const float*)d_in[4];
  const float* b1    = (const float*)d_in[5];
  const float* W2    = (const float*)d_in[6];
  const float* b2    = (const float*)d_in[7];
  const float* W3    = (const float*)d_in[8];
  const float* b3    = (const float*)d_in[9];
  const float* W4    = (const float*)d_in[10];
  const float* b4    = (const float*)d_in[11];
  float* xout = (float*)d_out;

  char* ws = (char*)d_ws;
  const size_t MB = 1024 * 1024;
  const size_t KB = 1024;
  u16* base16 = (u16*)(ws + 0);                       // 2 MiB
  u16* w1t = (u16*)(ws + 2 * MB);                     // 2 MiB each
  u16* w2t = (u16*)(ws + 4 * MB);
  u16* w3t = (u16*)(ws + 6 * MB);
  u16* hB  = (u16*)(ws + 8 * MB);
  u16* hC  = (u16*)(ws + 10 * MB);
  u16* tvecb = (u16*)(ws + 12 * MB);                  // 100 KiB
  u16* wxa = (u16*)(ws + 12 * MB + 128 * KB);         // 2 KiB
  u16* wxb = (u16*)(ws + 12 * MB + 132 * KB);         // 2 KiB
  float* vacc = (float*)(ws + 12 * MB + 192 * KB);    // 2 x 8 KiB
  float* xcur = (float*)(ws + 12 * MB + 256 * KB);    // 2 x 8 KiB

  transpose_w<<<dim3(32, 32, 3), 256, 0, stream>>>(W1, W2, W3, w1t, w2t, w3t);
  base_gemm<<<dim3(16, 16), 256, 0, stream>>>(state, W0, b0, base16);
  tvec_kernel<<<dim3(NSTEP + 1, 4), 256, 0, stream>>>(W0, tvecb, wxa, wxb);

  for (int s = 0; s < NSTEP; ++s) {
    float* xrd = xcur + ((s + 1) & 1) * 2048;  // (s-1)&1 parity
    float* xwr = xcur + (s & 1) * 2048;
    float* vpr = vacc + ((s + 1) & 1) * 2048;
    float* vcu = vacc + (s & 1) * 2048;
    gemm_l1<<<dim3(16, 16), 512, 0, stream>>>(base16, tvecb, wxa, wxb, x0, xrd,
                                              xwr, vpr, b4, w1t, b1, hB, s);
    gemm_l2<<<dim3(16, 16), 512, 0, stream>>>(hB, w2t, b2, hC, vcu);
    gemm_l3<<<dim3(16, 16), 512, 0, stream>>>(hC, w3t, b3, W4, vcu);
  }
  final_x<<<dim3(8), 256, 0, stream>>>(xcur + 2048, vacc + 2048, b4, xout);
}

// Round 8
// 1859.668 us; speedup vs baseline: 3.7867x; 1.2213x over previous
//
#include <hip/hip_runtime.h>

// ---------------------------------------------------------------------------
// FlowMatchingShield: 50-step Euler sampler over a 5-layer MLP.
// Round 8: consolidation of measured-best pieces on the round-0 skeleton
// (best measured: 1840us). Per step: l1,l2 = round-0 gemm_mfma (verbatim,
// 10us best of 3 designs tried); l3 = round-7 head-fused GEMM (kills h3f
// 4MB write+read); tail = slim x-update + bf16 h0-row build (2KB/row reads
// vs 8KB fp32). Double-buffered xcur/vacc parities -> race-free, tail zeroes
// next parity. Fast prologue (round-7 base_gemm 6us vs round-0 60us).
// 204 dispatches (l1,l2,l3,tail x50 + 4). Persistent-kernel path falsified
// rounds 4-6 (coherent traffic lands in HBM: 87-120us/step).
// ---------------------------------------------------------------------------

typedef __bf16 bf16x8 __attribute__((ext_vector_type(8)));
typedef float  f32x4  __attribute__((ext_vector_type(4)));
typedef float  f32x2  __attribute__((ext_vector_type(2)));
typedef unsigned short u16;
typedef u16 u16x8 __attribute__((ext_vector_type(8)));
typedef u16 u16x4 __attribute__((ext_vector_type(4)));
typedef u16 u16x2 __attribute__((ext_vector_type(2)));

#define H 1024
#define BATCH 1024
#define SDIM 254
#define NSTEP 50
#define DT 0.02f
#define LDP 40  // padded LDS row stride (elements): 80 B, 16B-aligned

__device__ __forceinline__ u16 f2bf(float f) {
  unsigned int u = __float_as_uint(f);
  return (u16)((u + 0x7FFFu + ((u >> 16) & 1u)) >> 16);
}

__device__ __forceinline__ float bf2f(u16 u) {
  return __uint_as_float(((unsigned int)u) << 16);
}

__device__ __forceinline__ float silu(float v) {
  return v / (1.0f + __expf(-v));
}

// --- one-time: W[k][n] fp32 -> WT[n][k] bf16, for W1..W3 (blockIdx.z picks) --
__global__ void transpose_w(const float* __restrict__ A, const float* __restrict__ B,
                            const float* __restrict__ C, u16* __restrict__ TA,
                            u16* __restrict__ TB, u16* __restrict__ TC) {
  const float* W = (blockIdx.z == 0) ? A : (blockIdx.z == 1) ? B : C;
  u16* T = (blockIdx.z == 0) ? TA : (blockIdx.z == 1) ? TB : TC;
  __shared__ float tile[32][33];
  const int n0 = blockIdx.x * 32, k0 = blockIdx.y * 32;
  const int tx = threadIdx.x & 31, ty = threadIdx.x >> 5;  // 32 x 8
#pragma unroll
  for (int i = 0; i < 4; ++i)
    tile[ty + 8 * i][tx] = W[(k0 + ty + 8 * i) * H + n0 + tx];
  __syncthreads();
#pragma unroll
  for (int i = 0; i < 4; ++i)
    T[(size_t)(n0 + ty + 8 * i) * H + k0 + tx] = f2bf(tile[tx][ty + 8 * i]);
}

// --- one-time: base16[b][n] = bf16(b0[n] + sum_k state[b][k]*W0[k][n]) ------
__global__ __launch_bounds__(256) void base_gemm(const float* __restrict__ state,
                                                 const float* __restrict__ W0,
                                                 const float* __restrict__ b0,
                                                 u16* __restrict__ base16) {
  __shared__ float Sst[64][68];
  __shared__ float Wl[64][68];
  const int bc = blockIdx.x, br = blockIdx.y, tid = threadIdx.x;
  const int myrow = (tid >> 4) * 4;
  const int mycol = (tid & 15) * 4;
  const int lr = tid >> 2;
  const int lc = (tid & 3) * 16;
  f32x4 acc[4] = {};

  for (int kc = 0; kc < 4; ++kc) {
    const int k0 = kc * 64;
#pragma unroll
    for (int j = 0; j < 8; ++j) {
      const int k = k0 + lc + 2 * j;
      float vx = 0.f, vy = 0.f;
      if (k + 1 < SDIM) {
        float2 v = *(const float2*)&state[(size_t)(br * 64 + lr) * SDIM + k];
        vx = v.x; vy = v.y;
      } else if (k < SDIM) {
        vx = state[(size_t)(br * 64 + lr) * SDIM + k];
      }
      Sst[lr][lc + 2 * j] = vx;
      Sst[lr][lc + 2 * j + 1] = vy;
    }
#pragma unroll
    for (int j = 0; j < 4; ++j) {
      f32x4 wv = {};
      if (k0 + lr < SDIM)
        wv = *(const f32x4*)&W0[(size_t)(k0 + lr) * H + bc * 64 + lc + 4 * j];
      *(f32x4*)&Wl[lr][lc + 4 * j] = wv;
    }
    __syncthreads();
#pragma unroll 4
    for (int kk = 0; kk < 64; kk += 4) {
      f32x4 sv[4], wv[4];
#pragma unroll
      for (int r = 0; r < 4; ++r) sv[r] = *(const f32x4*)&Sst[myrow + r][kk];
#pragma unroll
      for (int j = 0; j < 4; ++j) wv[j] = *(const f32x4*)&Wl[kk + j][mycol];
#pragma unroll
      for (int r = 0; r < 4; ++r)
#pragma unroll
        for (int j = 0; j < 4; ++j)
          acc[r] += sv[r][j] * wv[j];
    }
    __syncthreads();
  }

  const f32x4 bv = *(const f32x4*)&b0[bc * 64 + mycol];
#pragma unroll
  for (int r = 0; r < 4; ++r) {
    u16x4 o;
#pragma unroll
    for (int e = 0; e < 4; ++e) o[e] = f2bf(acc[r][e] + bv[e]);
    *(u16x4*)&base16[(size_t)(br * 64 + myrow + r) * H + bc * 64 + mycol] = o;
  }
}

// --- one-time: tvecb[s][h] (bf16) for s<50; s==50 writes wxa/wxb = bf16 W0 rows
__global__ void tvec_kernel(const float* __restrict__ W0, u16* __restrict__ tvecb,
                            u16* __restrict__ wxa, u16* __restrict__ wxb) {
  const int s = blockIdx.x;
  const int h = blockIdx.y * 256 + threadIdx.x;
  if (s == NSTEP) {
    wxa[h] = f2bf(W0[254 * H + h]);
    wxb[h] = f2bf(W0[255 * H + h]);
    return;
  }
  const float t = (float)s * DT;
  float acc = 0.0f;
#pragma unroll
  for (int j = 0; j < 32; ++j) {
    float fr = __expf((float)j * (-9.210340371976184f / 31.0f));
    float ang = t * fr;
    acc += __sinf(ang) * W0[(256 + j) * H + h] + __cosf(ang) * W0[(288 + j) * H + h];
  }
  tvecb[s * H + h] = f2bf(acc);
}

// --- main GEMM (round-0 verbatim, best measured): out = silu(A@BT^T + bias) --
// single-wave blocks (64 thr), 32x32 tile, BK=32, register prefetch, no barrier
__global__ __launch_bounds__(64) void gemm_mfma(const u16* __restrict__ A,
                                                const u16* __restrict__ BT,
                                                const float* __restrict__ bias,
                                                u16* __restrict__ out) {
  __shared__ u16 As[32 * LDP];
  __shared__ u16 Bs[32 * LDP];
  const int tid = threadIdx.x;
  const int bn = blockIdx.x, bm = blockIdx.y;
  const int lr = tid & 15, quad = tid >> 4;

  const int srow = tid >> 2;       // 0..15 (two rows: srow, srow+16)
  const int skc = (tid & 3) * 8;   // 0,8,16,24

  const u16* Ap = A + (size_t)(bm * 32 + srow) * H + skc;
  const u16* Bp = BT + (size_t)(bn * 32 + srow) * H + skc;

  f32x4 acc[2][2] = {};

  u16x8 ga0 = *(const u16x8*)(Ap);
  u16x8 ga1 = *(const u16x8*)(Ap + 16 * H);
  u16x8 gb0 = *(const u16x8*)(Bp);
  u16x8 gb1 = *(const u16x8*)(Bp + 16 * H);

  for (int kt = 0; kt < 32; ++kt) {
    *(u16x8*)&As[srow * LDP + skc] = ga0;
    *(u16x8*)&As[(srow + 16) * LDP + skc] = ga1;
    *(u16x8*)&Bs[srow * LDP + skc] = gb0;
    *(u16x8*)&Bs[(srow + 16) * LDP + skc] = gb1;
    if (kt < 31) {  // prefetch next K-tile into registers
      const int off = (kt + 1) * 32;
      ga0 = *(const u16x8*)(Ap + off);
      ga1 = *(const u16x8*)(Ap + 16 * H + off);
      gb0 = *(const u16x8*)(Bp + off);
      gb1 = *(const u16x8*)(Bp + 16 * H + off);
    }
    bf16x8 a0 = *(const bf16x8*)&As[lr * LDP + quad * 8];
    bf16x8 a1 = *(const bf16x8*)&As[(16 + lr) * LDP + quad * 8];
    bf16x8 b0 = *(const bf16x8*)&Bs[lr * LDP + quad * 8];
    bf16x8 b1 = *(const bf16x8*)&Bs[(16 + lr) * LDP + quad * 8];
    acc[0][0] = __builtin_amdgcn_mfma_f32_16x16x32_bf16(a0, b0, acc[0][0], 0, 0, 0);
    acc[0][1] = __builtin_amdgcn_mfma_f32_16x16x32_bf16(a0, b1, acc[0][1], 0, 0, 0);
    acc[1][0] = __builtin_amdgcn_mfma_f32_16x16x32_bf16(a1, b0, acc[1][0], 0, 0, 0);
    acc[1][1] = __builtin_amdgcn_mfma_f32_16x16x32_bf16(a1, b1, acc[1][1], 0, 0, 0);
  }

#pragma unroll
  for (int mt = 0; mt < 2; ++mt)
#pragma unroll
    for (int nt = 0; nt < 2; ++nt) {
      const int gm = bm * 32 + mt * 16 + quad * 4;
      const int gn = bn * 32 + nt * 16 + lr;
      const float bv = bias[gn];
      f32x4 v = acc[mt][nt];
#pragma unroll
      for (int r = 0; r < 4; ++r)
        out[(size_t)(gm + r) * H + gn] = f2bf(silu(v[r] + bv));
    }
}

// --- L3 (round-7 verified): GEMM @W3 + silu + W4-head -> atomicAdd vacc -----
__device__ __forceinline__ void mfma_all(const bf16x8 (&fa)[4][4],
                                         const bf16x8 (&fb)[4][4],
                                         f32x4 (&acc)[4][4]) {
#pragma unroll
  for (int it = 0; it < 4; ++it)
#pragma unroll
    for (int mt = 0; mt < 4; ++mt)
#pragma unroll
      for (int nt = 0; nt < 4; ++nt)
        acc[mt][nt] = __builtin_amdgcn_mfma_f32_16x16x32_bf16(fa[it][mt], fb[it][nt],
                                                              acc[mt][nt], 0, 0, 0);
}

__device__ __forceinline__ void load_frags(bf16x8 (&f)[4][4], const u16* __restrict__ P) {
#pragma unroll
  for (int it = 0; it < 4; ++it)
#pragma unroll
    for (int q = 0; q < 4; ++q)
      f[it][q] = *(const bf16x8*)(P + q * 16 * H + it * 32);
}

__global__ __launch_bounds__(512, 2) void gemm_l3(
    const u16* __restrict__ A, const u16* __restrict__ BT,
    const float* __restrict__ b3, const float* __restrict__ W4,
    float* __restrict__ vacc) {
  __shared__ float red[8][16][68];
  const int tid = threadIdx.x;
  const int w = tid >> 6, lane = tid & 63;
  const int lr = lane & 15, quad = lane >> 4;
  const int bn = blockIdx.x, bm = blockIdx.y;

  const u16* Ap = A + (size_t)(bm * 64 + lr) * H + w * 128 + quad * 8;
  const u16* Bp = BT + (size_t)(bn * 64 + lr) * H + w * 128 + quad * 8;
  bf16x8 fa[4][4], fb[4][4];
  load_frags(fa, Ap);
  load_frags(fb, Bp);
  f32x4 acc[4][4] = {};
  mfma_all(fa, fb, acc);

  const int m = tid >> 5, n0 = (tid & 31) * 2;
  const f32x2 bv = *(const f32x2*)&b3[bn * 64 + n0];
  const f32x4 w4v = *(const f32x4*)&W4[2 * (bn * 64 + n0)];
#pragma unroll
  for (int p = 0; p < 4; ++p) {
    if (p) __syncthreads();  // WAR vs previous phase's reads
#pragma unroll
    for (int nt = 0; nt < 4; ++nt)
#pragma unroll
      for (int r = 0; r < 4; ++r)
        red[w][quad * 4 + r][nt * 16 + lr] = acc[p][nt][r];
    __syncthreads();
    f32x2 sv = {};
#pragma unroll
    for (int ww = 0; ww < 8; ++ww) sv += *(const f32x2*)&red[ww][m][n0];
    const int gm = bm * 64 + p * 16 + m;
    const float t0 = silu(sv[0] + bv[0]), t1 = silu(sv[1] + bv[1]);
    float pv0 = t0 * w4v[0] + t1 * w4v[2];
    float pv1 = t0 * w4v[1] + t1 * w4v[3];
#pragma unroll
    for (int o = 16; o > 0; o >>= 1) {
      pv0 += __shfl_xor(pv0, o);
      pv1 += __shfl_xor(pv1, o);
    }
    if ((tid & 31) == 0) {
      atomicAdd(&vacc[2 * gm], pv0);
      atomicAdd(&vacc[2 * gm + 1], pv1);
    }
  }
}

// --- per-step tail (slim): x(s+1) = x(s) + dt*(vacc+b4); zero next-parity
// vacc; build h0(s+1) row (bf16 path, verified round 7). Race-free via
// double-buffered xcur/vacc parities (no intra-kernel WAR on shared data).
__global__ __launch_bounds__(256) void tail_kernel(
    const u16* __restrict__ base16, const u16* __restrict__ tvecb,
    const u16* __restrict__ wxa, const u16* __restrict__ wxb,
    const float* __restrict__ x0, float* __restrict__ xcur,
    float* __restrict__ vacc, const float* __restrict__ b4,
    u16* __restrict__ hA, float* __restrict__ xout, int s) {
  const int b = blockIdx.x, tid = threadIdx.x;
  float2 xc;
  if (s < 0) {
    xc = *(const float2*)&x0[2 * b];
  } else {
    float2 xp = *(const float2*)&xcur[(size_t)(s & 1) * 2048 + 2 * b];
    float2 vv = *(const float2*)&vacc[(size_t)(s & 1) * 2048 + 2 * b];
    xc.x = xp.x + DT * (vv.x + b4[0]);
    xc.y = xp.y + DT * (vv.y + b4[1]);
  }
  if (tid == 0) {
    *(float2*)&xcur[(size_t)((s + 1) & 1) * 2048 + 2 * b] = xc;
    float2 z = {0.f, 0.f};
    if (s < 0) {  // init: zero both parities
      *(float2*)&vacc[2 * b] = z;
      *(float2*)&vacc[2048 + 2 * b] = z;
    } else {
      *(float2*)&vacc[(size_t)((s + 1) & 1) * 2048 + 2 * b] = z;
    }
    if (s == NSTEP - 1) { xout[2 * b] = xc.x; xout[2 * b + 1] = xc.y; }
  }
  if (s < NSTEP - 1) {
    const int n = tid * 4;
    const int sp = s + 1;
    const u16x4 bs = *(const u16x4*)&base16[(size_t)b * H + n];
    const u16x4 tv = *(const u16x4*)&tvecb[(size_t)sp * H + n];
    const u16x4 wa = *(const u16x4*)&wxa[n];
    const u16x4 wb = *(const u16x4*)&wxb[n];
    u16x4 o;
#pragma unroll
    for (int e = 0; e < 4; ++e) {
      float v = bf2f(bs[e]) + bf2f(tv[e]) + xc.x * bf2f(wa[e]) + xc.y * bf2f(wb[e]);
      o[e] = f2bf(silu(v));
    }
    *(u16x4*)&hA[(size_t)b * H + n] = o;
  }
}

extern "C" void kernel_launch(void* const* d_in, const int* in_sizes, int n_in,
                              void* d_out, int out_size, void* d_ws, size_t ws_size,
                              hipStream_t stream) {
  const float* state = (const float*)d_in[0];
  const float* x0    = (const float*)d_in[1];
  const float* W0    = (const float*)d_in[2];
  const float* b0    = (const float*)d_in[3];
  const float* W1    = (const float*)d_in[4];
  const float* b1    = (const float*)d_in[5];
  const float* W2    = (const float*)d_in[6];
  const float* b2    = (const float*)d_in[7];
  const float* W3    = (const float*)d_in[8];
  const float* b3    = (const float*)d_in[9];
  const float* W4    = (const float*)d_in[10];
  const float* b4    = (const float*)d_in[11];
  float* xout = (float*)d_out;

  char* ws = (char*)d_ws;
  const size_t MB = 1024 * 1024;
  const size_t KB = 1024;
  u16* base16 = (u16*)(ws + 0);                       // 2 MiB
  u16* w1t = (u16*)(ws + 2 * MB);                     // 2 MiB each
  u16* w2t = (u16*)(ws + 4 * MB);
  u16* w3t = (u16*)(ws + 6 * MB);
  u16* hA  = (u16*)(ws + 8 * MB);
  u16* hB  = (u16*)(ws + 10 * MB);
  u16* hC  = (u16*)(ws + 12 * MB);
  u16* tvecb = (u16*)(ws + 14 * MB);                  // 100 KiB
  u16* wxa = (u16*)(ws + 14 * MB + 128 * KB);         // 2 KiB
  u16* wxb = (u16*)(ws + 14 * MB + 132 * KB);         // 2 KiB
  float* vacc = (float*)(ws + 14 * MB + 192 * KB);    // 2 x 8 KiB
  float* xcur = (float*)(ws + 14 * MB + 256 * KB);    // 2 x 8 KiB

  transpose_w<<<dim3(32, 32, 3), 256, 0, stream>>>(W1, W2, W3, w1t, w2t, w3t);
  base_gemm<<<dim3(16, 16), 256, 0, stream>>>(state, W0, b0, base16);
  tvec_kernel<<<dim3(NSTEP + 1, 4), 256, 0, stream>>>(W0, tvecb, wxa, wxb);
  // init: x(0) = x0, h0(0) -> hA, vacc zeroed (both parities)
  tail_kernel<<<BATCH, 256, 0, stream>>>(base16, tvecb, wxa, wxb, x0, xcur,
                                         vacc, b4, hA, xout, -1);

  for (int s = 0; s < NSTEP; ++s) {
    gemm_mfma<<<dim3(32, 32), 64, 0, stream>>>(hA, w1t, b1, hB);
    gemm_mfma<<<dim3(32, 32), 64, 0, stream>>>(hB, w2t, b2, hC);
    gemm_l3<<<dim3(16, 16), 512, 0, stream>>>(hC, w3t, b3, W4, vacc + (s & 1) * 2048);
    tail_kernel<<<BATCH, 256, 0, stream>>>(base16, tvecb, wxa, wxb, x0, xcur,
                                           vacc, b4, hA, xout, s);
  }
}